// Round 7
// baseline (268.831 us; speedup 1.0000x reference)
//
#include <hip/hip_runtime.h>

constexpr int B = 4, C = 128, H = 256, W = 512;
constexpr int HW = H * W;
constexpr int CHW = C * HW;

constexpr int SROW = 40;    // staged row width (floats); base col = c0-12 (16B aligned)
constexpr int SH_ = 34;     // staged rows; base row = r0-9
constexpr int NCHK = 6;     // DMA chunks (64 lanes x 16B = 256 floats each)
constexpr int SFLT = NCHK * 256;  // 1536 floats = 6 KB per wave-buffer
constexpr int CPG = 32;     // channels per block (grid.y = 4)

__device__ __forceinline__ void load_lds16(const float* g, float* l) {
  // per-lane global source; LDS dest = wave-uniform base + lane*16 (linear)
  __builtin_amdgcn_global_load_lds(
      (__attribute__((address_space(1))) void*)g,
      (__attribute__((address_space(3))) void*)l, 16, 0, 0);
}

__global__ __launch_bounds__(256) void warp_flow_kernel(
    const float* __restrict__ x, const float* __restrict__ flow,
    float* __restrict__ out) {
  // per-wave private double buffers: 4 waves x 2 x 6KB = 48 KB -> 3 blocks/CU
  __shared__ float sm[4][2][SFLT];

  // XCD-contiguous swizzle over the 512 tile-blocks (8 XCDs, round-robin)
  const int orig = blockIdx.x;
  const int swz = ((orig & 7) << 6) | (orig >> 3);  // bijective on [0,512)

  const int b = swz >> 7;          // image
  const int tid = swz & 127;       // 128 32x32 tiles per image
  const int r0b = (tid >> 4) * 32;
  const int c0b = (tid & 15) * 32;
  const int cg0 = blockIdx.y * CPG;

  const int t = threadIdx.x;
  const int wv = t >> 6;
  const int l = t & 63;
  // wave's private 16x16 patch within the 32x32 block tile
  const int r0 = r0b + ((wv >> 1) << 4);
  const int c0 = c0b + ((wv & 1) << 4);
  const int lw = l & 15;   // pixel col
  const int lr = l >> 4;   // pixel row base (0..3), rows lr + 4k

  // ---- per-pixel precompute (4 px/thread), channel-invariant ----
  float wa0[4], wb0[4], wa1[4], wb1[4];
  int ob0[4], ob1[4], pout[4];  // wave-buffer float offsets (or plane offs if fb)
  unsigned fb = 0;

#pragma unroll
  for (int k = 0; k < 4; ++k) {
    const int h = r0 + lr + 4 * k;
    const int w = c0 + lw;

    const int fidx = ((b * 2) * H + h) * W + w;
    const float flx = flow[fidx];
    const float fly = flow[fidx + HW];

    // replicate reference arithmetic (fp32, align_corners=True round trip)
    const float gx = (-1.0f + 2.0f * (float)w / (float)(W - 1)) + flx * 2.0f / (float)(W - 1);
    const float gy = (-1.0f + 2.0f * (float)h / (float)(H - 1)) + fly * 2.0f / (float)(H - 1);
    const float fx = (gx + 1.0f) * 0.5f * (float)(W - 1);
    const float fy = (gy + 1.0f) * 0.5f * (float)(H - 1);

    const float x0f = floorf(fx), y0f = floorf(fy);
    const float x1f = x0f + 1.0f, y1f = y0f + 1.0f;
    const float wx1 = fx - x0f, wx0 = 1.0f - wx1;
    const float wy1 = fy - y0f, wy0 = 1.0f - wy1;

    const bool vx0 = (x0f >= 0.0f) && (x0f <= (float)(W - 1));
    const bool vx1 = (x1f >= 0.0f) && (x1f <= (float)(W - 1));
    const bool vy0 = (y0f >= 0.0f) && (y0f <= (float)(H - 1));
    const bool vy1 = (y1f >= 0.0f) && (y1f <= (float)(H - 1));

    float a00 = wx0 * wy0 * ((vx0 && vy0) ? 1.0f : 0.0f);
    float a10 = wx1 * wy0 * ((vx1 && vy0) ? 1.0f : 0.0f);
    float a01 = wx0 * wy1 * ((vx0 && vy1) ? 1.0f : 0.0f);
    float a11 = wx1 * wy1 * ((vx1 && vy1) ? 1.0f : 0.0f);

    const float msum = a00 + a10 + a01 + a11;
    const float mask = (msum >= 0.9999f) ? 1.0f : 0.0f;
    a00 *= mask; a10 *= mask; a01 *= mask; a11 *= mask;

    const int ix0 = min(max((int)x0f, 0), W - 1);
    const int ix1 = min(max((int)x1f, 0), W - 1);
    const int iy0 = min(max((int)y0f, 0), H - 1);
    const int iy1 = min(max((int)y1f, 0), H - 1);

    // paired cols (bx, bx+1); fold clamp-routing into weights (bit-exact:
    // the clamped-away corner's weight is already 0)
    const int bx = min(ix0, W - 2);
    const int d0 = ix0 - bx;
    const int d1 = ix1 - bx;
    wa0[k] = (d0 ? 0.0f : a00) + (d1 ? 0.0f : a10);
    wb0[k] = (d0 ? a00 : 0.0f) + (d1 ? a10 : 0.0f);
    wa1[k] = (d0 ? 0.0f : a01) + (d1 ? 0.0f : a11);
    wb1[k] = (d0 ? a01 : 0.0f) + (d1 ? a11 : 0.0f);

    const int lbx = bx - (c0 - 12);
    const int l0y = iy0 - (r0 - 9);
    const int l1y = iy1 - (r0 - 9);
    const bool intile = (lbx >= 0) & (lbx <= SROW - 2) & (l0y >= 0) & (l1y <= SH_ - 1);

    if (intile) {
      ob0[k] = l0y * SROW + lbx;
      ob1[k] = l1y * SROW + lbx;
    } else {  // |flow| beyond halo (never for N(0,1) data, but must be correct)
      ob0[k] = iy0 * W + bx;
      ob1[k] = iy1 * W + bx;
      fb |= (1u << k);
    }
    pout[k] = h * W + w;
  }

  // chunk source offsets (channel-invariant part); lane l covers floats
  // [j*256 + l*4 .. +4) of the 34x40 staged tile (vc multiple of 4 -> 16B ok)
  int flat[NCHK];
#pragma unroll
  for (int j = 0; j < NCHK; ++j) {
    const int s = j * 256 + l * 4;
    const int vr = s / SROW;
    const int vc = s - vr * SROW;
    flat[j] = (r0 - 9 + vr) * W + (c0 - 12 + vc);
  }
  // interior waves need no per-channel clamping (wave-uniform test)
  const bool interior = (r0 >= 16) && (r0 <= H - 32) && (c0 >= 16) && (c0 <= W - 32);

  const float* __restrict__ xb = x + (size_t)b * CHW;
  float* __restrict__ wbuf0 = &sm[wv][0][0];
  float* __restrict__ wbuf1 = &sm[wv][1][0];

  auto stage = [&](int c, float* buf) {
    const int cHW = c * HW;
#pragma unroll
    for (int j = 0; j < NCHK; ++j) {
      int off = flat[j] + cHW;
      if (!interior) off = min(max(off, 0), CHW - 4);  // memory-safe; clamped slots unconsumed
      load_lds16(xb + off, buf + j * 256);
    }
  };

  // ---- prologue: stage first two channels ----
  stage(cg0, wbuf0);
  stage(cg0 + 1, wbuf1);

  // ---- barrier-free per-wave pipelined channel loop ----
  for (int i = 0; i < CPG; ++i) {
    const int c = cg0 + i;
    const float* __restrict__ sp = (i & 1) ? wbuf1 : wbuf0;

    // loads retire in order: <=6 outstanding => this buffer's 6 DMAs landed
    if (i + 1 < CPG) {
      asm volatile("s_waitcnt vmcnt(6)" ::: "memory");
    } else {
      asm volatile("s_waitcnt vmcnt(0)" ::: "memory");
    }
    __builtin_amdgcn_sched_barrier(0);

    const float* __restrict__ xp = xb + (size_t)c * HW;
    float* __restrict__ op = out + ((size_t)b * C + c) * HW;

#pragma unroll
    for (int k = 0; k < 4; ++k) {
      float e00, e01, e10, e11;
      if (!((fb >> k) & 1u)) {
        e00 = sp[ob0[k]]; e01 = sp[ob0[k] + 1];  // -> ds_read2_b32
        e10 = sp[ob1[k]]; e11 = sp[ob1[k] + 1];
      } else {  // rare far-displacement fallback (global gather)
        e00 = xp[ob0[k]]; e01 = xp[ob0[k] + 1];
        e10 = xp[ob1[k]]; e11 = xp[ob1[k] + 1];
      }
      const float r = wa0[k] * e00 + wb0[k] * e01 + wa1[k] * e10 + wb1[k] * e11;
      __builtin_nontemporal_store(r, op + pout[k]);
    }

    if (i + 2 < CPG) {
      __builtin_amdgcn_sched_barrier(0);
      stage(c + 2, (i & 1) ? wbuf1 : wbuf0);  // overwrite just-consumed buffer
    }
  }
}

extern "C" void kernel_launch(void* const* d_in, const int* in_sizes, int n_in,
                              void* d_out, int out_size, void* d_ws, size_t ws_size,
                              hipStream_t stream) {
  const float* x = (const float*)d_in[0];
  const float* flow = (const float*)d_in[1];
  float* out = (float*)d_out;
  dim3 grid((H / 32) * (W / 32) * B, C / CPG);  // (512, 4)
  warp_flow_kernel<<<grid, dim3(256), 0, stream>>>(x, flow, out);
}

// Round 8
// 234.168 us; speedup vs baseline: 1.1480x; 1.1480x over previous
//
#include <hip/hip_runtime.h>

constexpr int B = 4, C = 128, H = 256, W = 512;
constexpr int HW = H * W;
constexpr int CHW = C * HW;

constexpr int TW = 64, TH = 16;   // pixel tile per block
constexpr int HALO = 8;           // covers |flow| <= ~8 px; else global fallback
constexpr int SH_ = 34;           // staged rows; base row = r0-9
constexpr int SW2 = 88;           // staged cols (floats); base col = c0-12, 16B aligned
constexpr int LPR = 22;           // 16B lane-slots per row
constexpr int SLOTS = SH_ * LPR;  // 748 slots
constexpr int NCH = 3;            // DMA chunks per wave (256-slot chunks)
constexpr int SFL = NCH * 1024;   // 3072 floats per buffer (12 KB)
constexpr int CPG = 32;           // channels per block (grid.y = 4)

__device__ __forceinline__ void load_lds16(const float* g, float* l) {
  // 16B per lane; LDS dest = wave-uniform base + lane*16 (linear)
  __builtin_amdgcn_global_load_lds(
      (__attribute__((address_space(1))) void*)g,
      (__attribute__((address_space(3))) void*)l, 16, 0, 0);
}

__global__ __launch_bounds__(256) void warp_flow_kernel(
    const float* __restrict__ x, const float* __restrict__ flow,
    float* __restrict__ out) {
  __shared__ float sm[3][SFL];  // depth-3, 36 KB -> 4 blocks/CU

  // XCD-contiguous swizzle over 512 tiles (8 XCDs, round-robin dispatch)
  const int orig = blockIdx.x;
  const int swz = ((orig & 7) << 6) | (orig >> 3);  // bijective on [0,512)

  const int b = swz >> 7;
  const int tid = swz & 127;
  const int r0 = (tid >> 3) * TH;
  const int c0 = (tid & 7) * TW;
  const int cg0 = blockIdx.y * CPG;

  const int t = threadIdx.x;
  const int lw = t & 63;
  const int lr = t >> 6;

  // ---- per-pixel precompute (4 px/thread), channel-invariant ----
  float wa0[4], wb0[4], wa1[4], wb1[4];
  int ob0[4], ob1[4], pout[4];  // LDS elem offsets, or global plane offs if fb
  unsigned fb = 0;

#pragma unroll
  for (int k = 0; k < 4; ++k) {
    const int h = r0 + lr + 4 * k;
    const int w = c0 + lw;

    const int fidx = ((b * 2) * H + h) * W + w;
    const float flx = flow[fidx];
    const float fly = flow[fidx + HW];

    // replicate reference arithmetic (fp32, align_corners=True round trip)
    const float gx = (-1.0f + 2.0f * (float)w / (float)(W - 1)) + flx * 2.0f / (float)(W - 1);
    const float gy = (-1.0f + 2.0f * (float)h / (float)(H - 1)) + fly * 2.0f / (float)(H - 1);
    const float fx = (gx + 1.0f) * 0.5f * (float)(W - 1);
    const float fy = (gy + 1.0f) * 0.5f * (float)(H - 1);

    const float x0f = floorf(fx), y0f = floorf(fy);
    const float x1f = x0f + 1.0f, y1f = y0f + 1.0f;
    const float wx1 = fx - x0f, wx0 = 1.0f - wx1;
    const float wy1 = fy - y0f, wy0 = 1.0f - wy1;

    const bool vx0 = (x0f >= 0.0f) && (x0f <= (float)(W - 1));
    const bool vx1 = (x1f >= 0.0f) && (x1f <= (float)(W - 1));
    const bool vy0 = (y0f >= 0.0f) && (y0f <= (float)(H - 1));
    const bool vy1 = (y1f >= 0.0f) && (y1f <= (float)(H - 1));

    float a00 = wx0 * wy0 * ((vx0 && vy0) ? 1.0f : 0.0f);
    float a10 = wx1 * wy0 * ((vx1 && vy0) ? 1.0f : 0.0f);
    float a01 = wx0 * wy1 * ((vx0 && vy1) ? 1.0f : 0.0f);
    float a11 = wx1 * wy1 * ((vx1 && vy1) ? 1.0f : 0.0f);

    const float msum = a00 + a10 + a01 + a11;
    const float mask = (msum >= 0.9999f) ? 1.0f : 0.0f;
    a00 *= mask; a10 *= mask; a01 *= mask; a11 *= mask;

    const int ix0 = min(max((int)x0f, 0), W - 1);
    const int ix1 = min(max((int)x1f, 0), W - 1);
    const int iy0 = min(max((int)y0f, 0), H - 1);
    const int iy1 = min(max((int)y1f, 0), H - 1);

    // paired cols (bx, bx+1); fold clamp-routing into weights (bit-exact:
    // a clamped-away corner's weight is already 0)
    const int bx = min(ix0, W - 2);
    const int d0 = ix0 - bx;
    const int d1 = ix1 - bx;
    wa0[k] = (d0 ? 0.0f : a00) + (d1 ? 0.0f : a10);
    wb0[k] = (d0 ? a00 : 0.0f) + (d1 ? a10 : 0.0f);
    wa1[k] = (d0 ? 0.0f : a01) + (d1 ? 0.0f : a11);
    wb1[k] = (d0 ? a01 : 0.0f) + (d1 ? a11 : 0.0f);

    const int lbx = bx - (c0 - 12);
    const int l0y = iy0 - (r0 - 9);
    const int l1y = iy1 - (r0 - 9);
    const bool intile = (lbx >= 0) & (lbx <= SW2 - 2) & (l0y >= 0) & (l1y <= SH_ - 1);

    if (intile) {
      ob0[k] = l0y * SW2 + lbx;
      ob1[k] = l1y * SW2 + lbx;
    } else {  // |flow| beyond halo: global fallback (adds to vmcnt -> over-wait, safe)
      ob0[k] = iy0 * W + bx;
      ob1[k] = iy1 * W + bx;
      fb |= (1u << k);
    }
    pout[k] = h * W + w;
  }

  // staging source offsets (channel-invariant part); thread t covers slots
  // t, t+256, t+512 -> per wave 3 chunks, LDS dest linear in slot order
  int flat[NCH];
#pragma unroll
  for (int j = 0; j < NCH; ++j) {
    const int s = t + 256 * j;
    const int vr = s / LPR;
    const int vc4 = (s - vr * LPR) * 4;
    flat[j] = (r0 - 9 + vr) * W + (c0 - 12 + vc4);
  }
  const int wvbase = (t >> 6) * 256;  // wave-uniform float offset within chunk
  const float* __restrict__ xb = x + (size_t)b * CHW;

  auto stage = [&](int c, float* buf) {
    const int cHW = c * HW;
#pragma unroll
    for (int j = 0; j < NCH; ++j) {
      const int off = min(max(flat[j] + cHW, 0), CHW - 4);  // safe; clamped slots unconsumed
      load_lds16(xb + off, buf + j * 1024 + wvbase);
    }
  };

  // ---- prologue: stage first two channels (depth-3 pipeline) ----
  stage(cg0, sm[0]);
  stage(cg0 + 1, sm[1]);

  // ---- channel loop: counted vmcnt (never waits on stores), raw barriers ----
  for (int i = 0; i < CPG; ++i) {
    const int c = cg0 + i;

    if (i + 2 < CPG) stage(c + 2, sm[(i + 2) % 3]);

    // per-wave queue (oldest->newest) at this point, steady state:
    // ch_i(3), st_{i-2}(4), ch_{i+1}(3), st_{i-1}(4), ch_{i+2}(3) = 17
    // need ch_i retired -> allow 14 outstanding. Stores are NOT waited on.
    if (i == 0)       asm volatile("s_waitcnt vmcnt(6)"  ::: "memory");
    else if (i == 1)  asm volatile("s_waitcnt vmcnt(10)" ::: "memory");
    else if (i < 30)  asm volatile("s_waitcnt vmcnt(14)" ::: "memory");
    else if (i == 30) asm volatile("s_waitcnt vmcnt(11)" ::: "memory");
    else              asm volatile("s_waitcnt vmcnt(8)"  ::: "memory");
    __builtin_amdgcn_sched_barrier(0);
    __builtin_amdgcn_s_barrier();  // all waves' ch_i chunks landed

    const float* __restrict__ sp = sm[i % 3];
    const float* __restrict__ xp = xb + (size_t)c * HW;
    float* __restrict__ op = out + ((size_t)b * C + c) * HW;

#pragma unroll
    for (int k = 0; k < 4; ++k) {
      float e00, e01, e10, e11;
      if (!((fb >> k) & 1u)) {
        e00 = sp[ob0[k]]; e01 = sp[ob0[k] + 1];  // ds_read2_b32
        e10 = sp[ob1[k]]; e11 = sp[ob1[k] + 1];
      } else {  // rare far-displacement fallback
        e00 = xp[ob0[k]]; e01 = xp[ob0[k] + 1];
        e10 = xp[ob1[k]]; e11 = xp[ob1[k] + 1];
      }
      const float r = wa0[k] * e00 + wb0[k] * e01 + wa1[k] * e10 + wb1[k] * e11;
      __builtin_nontemporal_store(r, op + pout[k]);
    }
    __builtin_amdgcn_s_barrier();  // buf[i%3] free for iter i+1's stage
  }
}

extern "C" void kernel_launch(void* const* d_in, const int* in_sizes, int n_in,
                              void* d_out, int out_size, void* d_ws, size_t ws_size,
                              hipStream_t stream) {
  const float* x = (const float*)d_in[0];
  const float* flow = (const float*)d_in[1];
  float* out = (float*)d_out;
  dim3 grid((H / TH) * (W / TW) * B, C / CPG);  // (512, 4)
  warp_flow_kernel<<<grid, dim3(256), 0, stream>>>(x, flow, out);
}

// Round 9
// 163.304 us; speedup vs baseline: 1.6462x; 1.4339x over previous
//
#include <hip/hip_runtime.h>

constexpr int B = 4, C = 128, H = 256, W = 512;
constexpr int HW = H * W;
constexpr int CPB = 32;  // channels per blockIdx.y slice (grid.y = 4)

typedef float f2 __attribute__((ext_vector_type(2), aligned(4)));

__global__ __launch_bounds__(256) void warp_flow_kernel(
    const float* __restrict__ x, const float* __restrict__ flow,
    float* __restrict__ out) {
  // XCD-aware swizzle: XCD k owns 256 contiguous blocks (contiguous image
  // rows) -> each x row fetched by exactly one XCD L2 (R2: 570->143MB).
  const int orig = blockIdx.x;
  const int swz = ((orig & 7) << 8) | (orig >> 3);  // bijective on [0,2048)

  // Block = 2 rows x 128 cols. Wave = 2 rows x 32 cols (TA line-touch
  // minimizing footprint: gather col-span 32 caps lines/row at ~3 vs ~5).
  const int b = swz >> 9;          // image
  const int idx = swz & 511;       // 512 blocks per image
  const int rp = idx >> 2;         // row-pair index (0..127)
  const int cg = idx & 3;          // col group of 128

  const int t = threadIdx.x;
  const int wv = t >> 6;
  const int l = t & 63;
  const int h = rp * 2 + (l >> 5);           // 2 rows per wave
  const int w = cg * 128 + wv * 32 + (l & 31);  // 32 cols per wave

  // flow layout [B,2,H,W]
  const int fidx = ((b * 2) * H + h) * W + w;
  const float flx = flow[fidx];
  const float fly = flow[fidx + HW];

  // replicate reference arithmetic (fp32, align_corners=True round trip)
  const float gx = (-1.0f + 2.0f * (float)w / (float)(W - 1)) + flx * 2.0f / (float)(W - 1);
  const float gy = (-1.0f + 2.0f * (float)h / (float)(H - 1)) + fly * 2.0f / (float)(H - 1);
  const float fx = (gx + 1.0f) * 0.5f * (float)(W - 1);
  const float fy = (gy + 1.0f) * 0.5f * (float)(H - 1);

  const float x0f = floorf(fx), y0f = floorf(fy);
  const float x1f = x0f + 1.0f, y1f = y0f + 1.0f;
  const float wx1 = fx - x0f, wx0 = 1.0f - wx1;
  const float wy1 = fy - y0f, wy0 = 1.0f - wy1;

  const bool vx0 = (x0f >= 0.0f) && (x0f <= (float)(W - 1));
  const bool vx1 = (x1f >= 0.0f) && (x1f <= (float)(W - 1));
  const bool vy0 = (y0f >= 0.0f) && (y0f <= (float)(H - 1));
  const bool vy1 = (y1f >= 0.0f) && (y1f <= (float)(H - 1));

  float a00 = wx0 * wy0 * ((vx0 && vy0) ? 1.0f : 0.0f);
  float a10 = wx1 * wy0 * ((vx1 && vy0) ? 1.0f : 0.0f);
  float a01 = wx0 * wy1 * ((vx0 && vy1) ? 1.0f : 0.0f);
  float a11 = wx1 * wy1 * ((vx1 && vy1) ? 1.0f : 0.0f);

  const float msum = a00 + a10 + a01 + a11;
  const float mask = (msum >= 0.9999f) ? 1.0f : 0.0f;
  a00 *= mask; a10 *= mask; a01 *= mask; a11 *= mask;

  const int ix0 = min(max((int)x0f, 0), W - 1);
  const int ix1 = min(max((int)x1f, 0), W - 1);
  const int iy0 = min(max((int)y0f, 0), H - 1);
  const int iy1 = min(max((int)y1f, 0), H - 1);

  // fold column clamp into pair weights: read cols (bx, bx+1), route by d0/d1
  const int bx = min(ix0, W - 2);
  const int d0 = ix0 - bx;  // 0 or 1
  const int d1 = ix1 - bx;  // 0 or 1
  const float wa0 = (d0 ? 0.0f : a00) + (d1 ? 0.0f : a10);
  const float wb0 = (d0 ? a00 : 0.0f) + (d1 ? a10 : 0.0f);
  const float wa1 = (d0 ? 0.0f : a01) + (d1 ? 0.0f : a11);
  const float wb1 = (d0 ? a01 : 0.0f) + (d1 ? a11 : 0.0f);

  const int o0 = iy0 * W + bx;  // row-y0 pair base (in-bounds: bx+1 <= W-1)
  const int o1 = iy1 * W + bx;  // row-y1 pair base

  const int cg0 = blockIdx.y * CPB;
  const float* __restrict__ xp = x + ((size_t)b * C + cg0) * HW;
  float* __restrict__ op = out + ((size_t)b * C + cg0) * HW + h * W + w;

#pragma unroll 8
  for (int c = 0; c < CPB; ++c) {
    const int coff = c * HW;
    const f2 va = *reinterpret_cast<const f2*>(xp + coff + o0);  // dwordx2
    const f2 vb = *reinterpret_cast<const f2*>(xp + coff + o1);  // dwordx2
    const float r = wa0 * va[0] + wb0 * va[1] + wa1 * vb[0] + wb1 * vb[1];
    __builtin_nontemporal_store(r, op + coff);
  }
}

extern "C" void kernel_launch(void* const* d_in, const int* in_sizes, int n_in,
                              void* d_out, int out_size, void* d_ws, size_t ws_size,
                              hipStream_t stream) {
  const float* x = (const float*)d_in[0];
  const float* flow = (const float*)d_in[1];
  float* out = (float*)d_out;
  const int npix = B * H * W;                 // 524288
  dim3 grid(npix / 256, C / CPB);             // (2048, 4)
  warp_flow_kernel<<<grid, dim3(256), 0, stream>>>(x, flow, out);
}

// Round 10
// 146.744 us; speedup vs baseline: 1.8320x; 1.1129x over previous
//
#include <hip/hip_runtime.h>

constexpr int B = 4, C = 128, H = 256, W = 512;
constexpr int HW = H * W;
constexpr int CPB = 32;  // channels per blockIdx.y slice (grid.y = 4)

typedef float f2 __attribute__((ext_vector_type(2), aligned(8)));
typedef float f2u __attribute__((ext_vector_type(2), aligned(4)));

__global__ __launch_bounds__(256) void warp_flow_kernel(
    const float* __restrict__ x, const float* __restrict__ flow,
    float* __restrict__ out) {
  // 1024 tiles (256 per image, 16x16 tiles of 16rows x 32cols).
  // XCD-aware swizzle: XCD k owns 128 contiguous tiles = 128 contiguous
  // image rows of one image -> halo rows shared within one L2.
  const int orig = blockIdx.x;
  const int swz = ((orig & 7) << 7) | (orig >> 3);  // bijective on [0,1024)

  const int b = swz >> 8;        // image
  const int tid = swz & 255;     // tile within image
  const int tr = tid >> 4;       // tile row (16 rows each)
  const int tc = tid & 15;       // tile col (32 cols each)

  const int t = threadIdx.x;
  // wave = 4 rows x 16 threads x 2 px-cols; block = 4 waves = 16 rows
  const int h = tr * 16 + ((t >> 6) << 2) + ((t & 63) >> 4);
  const int w0 = tc * 32 + (t & 15) * 2;

  // flow layout [B,2,H,W]; load both pixels' flow as f2
  const int fidx = ((b * 2) * H + h) * W + w0;
  const f2 flx = *reinterpret_cast<const f2*>(flow + fidx);
  const f2 fly = *reinterpret_cast<const f2*>(flow + fidx + HW);

  float wa0[2], wb0[2], wa1[2], wb1[2];
  int o0[2], o1[2];

#pragma unroll
  for (int j = 0; j < 2; ++j) {
    const int w = w0 + j;
    // replicate reference arithmetic (fp32, align_corners=True round trip)
    const float gx = (-1.0f + 2.0f * (float)w / (float)(W - 1)) + flx[j] * 2.0f / (float)(W - 1);
    const float gy = (-1.0f + 2.0f * (float)h / (float)(H - 1)) + fly[j] * 2.0f / (float)(H - 1);
    const float fx = (gx + 1.0f) * 0.5f * (float)(W - 1);
    const float fy = (gy + 1.0f) * 0.5f * (float)(H - 1);

    const float x0f = floorf(fx), y0f = floorf(fy);
    const float x1f = x0f + 1.0f, y1f = y0f + 1.0f;
    const float wx1 = fx - x0f, wx0 = 1.0f - wx1;
    const float wy1 = fy - y0f, wy0 = 1.0f - wy1;

    const bool vx0 = (x0f >= 0.0f) && (x0f <= (float)(W - 1));
    const bool vx1 = (x1f >= 0.0f) && (x1f <= (float)(W - 1));
    const bool vy0 = (y0f >= 0.0f) && (y0f <= (float)(H - 1));
    const bool vy1 = (y1f >= 0.0f) && (y1f <= (float)(H - 1));

    float a00 = wx0 * wy0 * ((vx0 && vy0) ? 1.0f : 0.0f);
    float a10 = wx1 * wy0 * ((vx1 && vy0) ? 1.0f : 0.0f);
    float a01 = wx0 * wy1 * ((vx0 && vy1) ? 1.0f : 0.0f);
    float a11 = wx1 * wy1 * ((vx1 && vy1) ? 1.0f : 0.0f);

    const float msum = a00 + a10 + a01 + a11;
    const float mask = (msum >= 0.9999f) ? 1.0f : 0.0f;
    a00 *= mask; a10 *= mask; a01 *= mask; a11 *= mask;

    const int ix0 = min(max((int)x0f, 0), W - 1);
    const int ix1 = min(max((int)x1f, 0), W - 1);
    const int iy0 = min(max((int)y0f, 0), H - 1);
    const int iy1 = min(max((int)y1f, 0), H - 1);

    // fold column clamp into pair weights: read cols (bx, bx+1)
    const int bx = min(ix0, W - 2);
    const int d0 = ix0 - bx;
    const int d1 = ix1 - bx;
    wa0[j] = (d0 ? 0.0f : a00) + (d1 ? 0.0f : a10);
    wb0[j] = (d0 ? a00 : 0.0f) + (d1 ? a10 : 0.0f);
    wa1[j] = (d0 ? 0.0f : a01) + (d1 ? 0.0f : a11);
    wb1[j] = (d0 ? a01 : 0.0f) + (d1 ? a11 : 0.0f);

    o0[j] = iy0 * W + bx;  // row-y0 pair base (bx+1 <= W-1 in-bounds)
    o1[j] = iy1 * W + bx;  // row-y1 pair base
  }

  const int cg0 = blockIdx.y * CPB;
  const float* __restrict__ xp = x + ((size_t)b * C + cg0) * HW;
  float* __restrict__ op = out + ((size_t)b * C + cg0) * HW + h * W + w0;

#pragma unroll 4
  for (int c = 0; c < CPB; ++c) {
    const int coff = c * HW;
    const f2u va0 = *reinterpret_cast<const f2u*>(xp + coff + o0[0]);
    const f2u vb0 = *reinterpret_cast<const f2u*>(xp + coff + o1[0]);
    const f2u va1 = *reinterpret_cast<const f2u*>(xp + coff + o0[1]);
    const f2u vb1 = *reinterpret_cast<const f2u*>(xp + coff + o1[1]);
    f2 r;
    r[0] = wa0[0] * va0[0] + wb0[0] * va0[1] + wa1[0] * vb0[0] + wb1[0] * vb0[1];
    r[1] = wa0[1] * va1[0] + wb0[1] * va1[1] + wa1[1] * vb1[0] + wb1[1] * vb1[1];
    __builtin_nontemporal_store(r, reinterpret_cast<f2*>(op + coff));  // dwordx2
  }
}

extern "C" void kernel_launch(void* const* d_in, const int* in_sizes, int n_in,
                              void* d_out, int out_size, void* d_ws, size_t ws_size,
                              hipStream_t stream) {
  const float* x = (const float*)d_in[0];
  const float* flow = (const float*)d_in[1];
  float* out = (float*)d_out;
  dim3 grid(1024, C / CPB);  // 256 tiles/image x 4 images, 4 channel groups
  warp_flow_kernel<<<grid, dim3(256), 0, stream>>>(x, flow, out);
}

// Round 11
// 129.844 us; speedup vs baseline: 2.0704x; 1.1302x over previous
//
#include <hip/hip_runtime.h>

constexpr int B = 4, C = 128, H = 256, W = 512;
constexpr int HW = H * W;
constexpr int CPB = 32;  // channels per blockIdx.y slice (grid.y = 4)

typedef float f4 __attribute__((ext_vector_type(4), aligned(16)));
typedef float f2u __attribute__((ext_vector_type(2), aligned(4)));

__global__ __launch_bounds__(256) void warp_flow_kernel(
    const float* __restrict__ x, const float* __restrict__ flow,
    float* __restrict__ out) {
  // 512 blocks: 128 tiles/image (16 rows x 64 cols) x 4 images.
  // XCD-aware swizzle: XCD k owns 64 contiguous tiles (= a contiguous row
  // band of one image) -> halo rows shared within one L2.
  const int orig = blockIdx.x;
  const int swz = ((orig & 7) << 6) | (orig >> 3);  // bijective on [0,512)

  const int b = swz >> 7;        // image
  const int tid = swz & 127;     // tile within image
  const int tr = tid >> 3;       // tile row (16 rows each)
  const int tc = tid & 7;        // tile col (64 cols each)

  const int t = threadIdx.x;
  // wave = 4 rows x 16 lanes x 4 px-cols; block = 4 waves = 16 rows
  const int h = tr * 16 + ((t >> 6) << 2) + ((t & 63) >> 4);
  const int w0 = tc * 64 + (t & 15) * 4;

  // flow layout [B,2,H,W]; 4 pixels' flow as f4 (w0 multiple of 4 -> aligned)
  const int fidx = ((b * 2) * H + h) * W + w0;
  const f4 flx = *reinterpret_cast<const f4*>(flow + fidx);
  const f4 fly = *reinterpret_cast<const f4*>(flow + fidx + HW);

  float wa0[4], wb0[4], wa1[4], wb1[4];
  int o0[4], o1[4];

#pragma unroll
  for (int j = 0; j < 4; ++j) {
    const int w = w0 + j;
    // replicate reference arithmetic (fp32, align_corners=True round trip)
    const float gx = (-1.0f + 2.0f * (float)w / (float)(W - 1)) + flx[j] * 2.0f / (float)(W - 1);
    const float gy = (-1.0f + 2.0f * (float)h / (float)(H - 1)) + fly[j] * 2.0f / (float)(H - 1);
    const float fx = (gx + 1.0f) * 0.5f * (float)(W - 1);
    const float fy = (gy + 1.0f) * 0.5f * (float)(H - 1);

    const float x0f = floorf(fx), y0f = floorf(fy);
    const float x1f = x0f + 1.0f, y1f = y0f + 1.0f;
    const float wx1 = fx - x0f, wx0 = 1.0f - wx1;
    const float wy1 = fy - y0f, wy0 = 1.0f - wy1;

    const bool vx0 = (x0f >= 0.0f) && (x0f <= (float)(W - 1));
    const bool vx1 = (x1f >= 0.0f) && (x1f <= (float)(W - 1));
    const bool vy0 = (y0f >= 0.0f) && (y0f <= (float)(H - 1));
    const bool vy1 = (y1f >= 0.0f) && (y1f <= (float)(H - 1));

    float a00 = wx0 * wy0 * ((vx0 && vy0) ? 1.0f : 0.0f);
    float a10 = wx1 * wy0 * ((vx1 && vy0) ? 1.0f : 0.0f);
    float a01 = wx0 * wy1 * ((vx0 && vy1) ? 1.0f : 0.0f);
    float a11 = wx1 * wy1 * ((vx1 && vy1) ? 1.0f : 0.0f);

    const float msum = a00 + a10 + a01 + a11;
    const float mask = (msum >= 0.9999f) ? 1.0f : 0.0f;
    a00 *= mask; a10 *= mask; a01 *= mask; a11 *= mask;

    const int ix0 = min(max((int)x0f, 0), W - 1);
    const int ix1 = min(max((int)x1f, 0), W - 1);
    const int iy0 = min(max((int)y0f, 0), H - 1);
    const int iy1 = min(max((int)y1f, 0), H - 1);

    // fold column clamp into pair weights: read cols (bx, bx+1)
    const int bx = min(ix0, W - 2);
    const int d0 = ix0 - bx;
    const int d1 = ix1 - bx;
    wa0[j] = (d0 ? 0.0f : a00) + (d1 ? 0.0f : a10);
    wb0[j] = (d0 ? a00 : 0.0f) + (d1 ? a10 : 0.0f);
    wa1[j] = (d0 ? 0.0f : a01) + (d1 ? 0.0f : a11);
    wb1[j] = (d0 ? a01 : 0.0f) + (d1 ? a11 : 0.0f);

    o0[j] = iy0 * W + bx;  // row-y0 pair base (bx+1 <= W-1 in-bounds)
    o1[j] = iy1 * W + bx;  // row-y1 pair base
  }

  const int cg0 = blockIdx.y * CPB;
  const float* __restrict__ xp = x + ((size_t)b * C + cg0) * HW;
  float* __restrict__ op = out + ((size_t)b * C + cg0) * HW + h * W + w0;

#pragma unroll 2
  for (int c = 0; c < CPB; ++c) {
    const int coff = c * HW;
    f4 r;
#pragma unroll
    for (int j = 0; j < 4; ++j) {
      const f2u va = *reinterpret_cast<const f2u*>(xp + coff + o0[j]);
      const f2u vb = *reinterpret_cast<const f2u*>(xp + coff + o1[j]);
      r[j] = wa0[j] * va[0] + wb0[j] * va[1] + wa1[j] * vb[0] + wb1[j] * vb[1];
    }
    __builtin_nontemporal_store(r, reinterpret_cast<f4*>(op + coff));  // dwordx4
  }
}

extern "C" void kernel_launch(void* const* d_in, const int* in_sizes, int n_in,
                              void* d_out, int out_size, void* d_ws, size_t ws_size,
                              hipStream_t stream) {
  const float* x = (const float*)d_in[0];
  const float* flow = (const float*)d_in[1];
  float* out = (float*)d_out;
  dim3 grid(512, C / CPB);  // 128 tiles/image x 4 images, 4 channel groups
  warp_flow_kernel<<<grid, dim3(256), 0, stream>>>(x, flow, out);
}